// Round 6
// baseline (187.472 us; speedup 1.0000x reference)
//
#include <hip/hip_runtime.h>
#include <math.h>

#define NB 4
#define NL 2048
#define ND 768
#define NH 12
#define NK 9
#define NIPG 64
#define NPAD 4
#define MT 112          // output rows per gemm_conv block (computes 128 v-rows)

typedef __attribute__((ext_vector_type(8))) short s16x8;
typedef __attribute__((ext_vector_type(4))) float f32x4;

__device__ __forceinline__ unsigned short f2bf(float f) {
  unsigned int u = __float_as_uint(f);
  unsigned int r = (u + 0x7FFFu + ((u >> 16) & 1u)) >> 16;
  return (unsigned short)r;
}
__device__ __forceinline__ float bf2f(unsigned short s) {
  return __uint_as_float(((unsigned int)s) << 16);
}

// ---------------------------------------------------------------------------
// Kernel 0: weight prep — pt_w -> ptb (bf16), pw_w -> pwb, ak_w -> akp
// (k-padded to 16 with zeros).
// ---------------------------------------------------------------------------
__global__ __launch_bounds__(256) void prep(const float* __restrict__ pt_w,
                                            const float* __restrict__ pw_w,
                                            const float* __restrict__ ak_w,
                                            unsigned short* __restrict__ ptb,
                                            unsigned short* __restrict__ pwb,
                                            unsigned short* __restrict__ akp) {
  const int t = blockIdx.x * 256 + threadIdx.x;
  if (t < ND * ND / 4) {
    float4 f = ((const float4*)pt_w)[t];
    ushort4 o; o.x = f2bf(f.x); o.y = f2bf(f.y); o.z = f2bf(f.z); o.w = f2bf(f.w);
    ((ushort4*)ptb)[t] = o;
  }
  if (t < NH * NIPG * NIPG / 4) {
    float4 f = ((const float4*)pw_w)[t];
    ushort4 o; o.x = f2bf(f.x); o.y = f2bf(f.y); o.z = f2bf(f.z); o.w = f2bf(f.w);
    ((ushort4*)pwb)[t] = o;
  }
  if (t < NH * 16 * NIPG) {
    const int h = t >> 10;
    const int r = t & 1023;
    const int k = r >> 6;
    const int i = r & 63;
    akp[t] = (k < NK) ? f2bf(ak_w[((size_t)h * NK + k) * NIPG + i]) : (unsigned short)0;
  }
}

// ---------------------------------------------------------------------------
// Kernel 1: dynamic conv weights (MFMA) + emits qb = bf16(query).
// ONE barrier total: ab accesses are wave-private (wave wv touches only rows
// [16wv,16wv+16)), so only the cross-wave qs staging needs a sync.  B-frags
// (pwb/akp) hoisted to kernel start so L2 latency overlaps staging.
// ---------------------------------------------------------------------------
__global__ __launch_bounds__(256) void attn_w(const float* __restrict__ q,
                                              const float* __restrict__ dw_w,
                                              const unsigned short* __restrict__ pwb,
                                              const float* __restrict__ pw_b,
                                              const unsigned short* __restrict__ akp,
                                              const float* __restrict__ ak_b,
                                              float* __restrict__ wout,
                                              unsigned short* __restrict__ qb) {
  __shared__ unsigned short qs[72][68];   // bf16, stride 68 rotates banks
  __shared__ unsigned char ab[8192];      // [64][64] bf16, byte ^= (row&7)<<4
  const int l0 = blockIdx.x * 64;
  const int h  = blockIdx.y;
  const int b  = blockIdx.z;
  const int d0 = h * NIPG;
  const int t  = threadIdx.x;
  const int lane = t & 63;
  const int wv = t >> 6;
  const int fr = lane & 15;
  const int fq = lane >> 4;

  // --- early global loads (consumed after compute phases; latency hidden) ---
  const unsigned short* pwh = pwb + (size_t)h * NIPG * NIPG;
  const unsigned short* akh = akp + (size_t)h * 16 * NIPG;
  s16x8 pv0[4], pv1[4];
#pragma unroll
  for (int n = 0; n < 4; ++n) {
    const int o = n * 16 + fr;
    pv0[n] = *(const s16x8*)&pwh[o * 64 + fq * 8];
    pv1[n] = *(const s16x8*)&pwh[o * 64 + 32 + fq * 8];
  }
  s16x8 ak0 = *(const s16x8*)&akh[fr * 64 + fq * 8];
  s16x8 ak1 = *(const s16x8*)&akh[fr * 64 + 32 + fq * 8];
  float dwk[NK];
#pragma unroll
  for (int k = 0; k < NK; ++k) dwk[k] = dw_w[(size_t)(d0 + lane) * NK + k];

  // --- stage q rows l0-4 .. l0+67 as bf16; rows [4,68) also emit to qb ---
  {
    const int sl = t >> 4;
    const int sc = (t & 15) * 4;
    for (int r = sl; r < 72; r += 16) {
      const int l = l0 - NPAD + r;
      ushort4 ub = make_ushort4(0, 0, 0, 0);
      if (l >= 0 && l < NL) {
        float4 val = *(const float4*)&q[((size_t)(b * NL + l)) * ND + d0 + sc];
        ub.x = f2bf(val.x); ub.y = f2bf(val.y); ub.z = f2bf(val.z); ub.w = f2bf(val.w);
        if (r >= NPAD && r < NPAD + 64)
          *(ushort4*)&qb[((size_t)(b * NL + l)) * ND + d0 + sc] = ub;
      }
      *(ushort4*)&qs[r][sc] = ub;
    }
  }
  __syncthreads();                 // the ONLY barrier

  // --- depthwise conv, rolling window; write bf16 swizzled (own rows) ---
  const int lset = wv * 16;
  {
    float win9[NK];
#pragma unroll
    for (int k = 0; k < NK; ++k) win9[k] = bf2f(qs[lset + k][lane]);
#pragma unroll
    for (int l2 = 0; l2 < 16; ++l2) {
      const int l = lset + l2;
      float s = 0.f;
#pragma unroll
      for (int k = 0; k < NK; ++k) s = fmaf(win9[k], dwk[k], s);
      const int byte = ((l * 64 + lane) * 2) ^ ((l & 7) << 4);
      *(unsigned short*)&ab[byte] = f2bf(s);
      if (l2 < 15) {
#pragma unroll
        for (int k = 0; k < NK - 1; ++k) win9[k] = win9[k + 1];
        win9[NK - 1] = bf2f(qs[lset + l2 + NK][lane]);
      }
    }
  }

  // --- MFMA #1: pw[l][o] = dw[l][:] . pw_w[h][o][:]  (A from own ab rows) ---
  s16x8 av0, av1;
  {
    const int row = lset + fr;
    const int b0 = ((row * 64 + fq * 8) * 2)      ^ ((row & 7) << 4);
    const int b1 = ((row * 64 + 32 + fq * 8) * 2) ^ ((row & 7) << 4);
    av0 = *(const s16x8*)&ab[b0];
    av1 = *(const s16x8*)&ab[b1];
  }
  f32x4 accp[4];
#pragma unroll
  for (int n = 0; n < 4; ++n) {
    accp[n] = (f32x4){0.f, 0.f, 0.f, 0.f};
    accp[n] = __builtin_amdgcn_mfma_f32_16x16x32_bf16(av0, pv0[n], accp[n], 0, 0, 0);
    accp[n] = __builtin_amdgcn_mfma_f32_16x16x32_bf16(av1, pv1[n], accp[n], 0, 0, 0);
  }

  // --- ca = (pw + pw_b) * q -> ab (own rows; in-wave DS ordering is safe) ---
#pragma unroll
  for (int n = 0; n < 4; ++n) {
    const int o = n * 16 + fr;
    const float pb = pw_b[d0 + o];
#pragma unroll
    for (int j = 0; j < 4; ++j) {
      const int row = lset + fq * 4 + j;
      const float ca = (accp[n][j] + pb) * bf2f(qs[row + NPAD][o]);
      const int byte = ((row * 64 + o) * 2) ^ ((row & 7) << 4);
      *(unsigned short*)&ab[byte] = f2bf(ca);
    }
  }

  // --- MFMA #2: kern[l][k] = ca[l][:] . ak_w[h][k][:]  (k padded to 16) ---
  f32x4 acck = (f32x4){0.f, 0.f, 0.f, 0.f};
  {
    const int row = lset + fr;
    const int b0 = ((row * 64 + fq * 8) * 2)      ^ ((row & 7) << 4);
    const int b1 = ((row * 64 + 32 + fq * 8) * 2) ^ ((row & 7) << 4);
    s16x8 a0 = *(const s16x8*)&ab[b0];
    s16x8 a1 = *(const s16x8*)&ab[b1];
    acck = __builtin_amdgcn_mfma_f32_16x16x32_bf16(a0, ak0, acck, 0, 0, 0);
    acck = __builtin_amdgcn_mfma_f32_16x16x32_bf16(a1, ak1, acck, 0, 0, 0);
  }

  // --- softmax over k (16-lane groups) + store ---
  const bool kvalid = fr < NK;
  const float akbv = kvalid ? ak_b[h * NK + fr] : 0.f;
#pragma unroll
  for (int j = 0; j < 4; ++j) {
    float val = acck[j] + akbv;
    float mv = kvalid ? val : -3.4e38f;
#pragma unroll
    for (int mm = 1; mm < 16; mm <<= 1) mv = fmaxf(mv, __shfl_xor(mv, mm));
    const float e = kvalid ? __expf(val - mv) : 0.f;
    float ssum = e;
#pragma unroll
    for (int mm = 1; mm < 16; mm <<= 1) ssum += __shfl_xor(ssum, mm);
    if (kvalid) {
      const int row = l0 + lset + fq * 4 + j;
      wout[(((size_t)(b * NL + row)) * NH + h) * NK + fr] = e / ssum;
    }
  }
}

// ---------------------------------------------------------------------------
// Kernel 2: fused v-GEMM + 9-tap span conv.  NO LDS staging: qb is
// LLC-resident (12.6MB), ptb L2-resident (1.2MB) -> fragments load directly
// global->VGPR, register-double-buffered, ZERO barriers in the K-loop.
// 128(M) x 64(N) tile, 4 waves x 32 rows; one sync before conv tail.
// ---------------------------------------------------------------------------
__global__ __launch_bounds__(256) void gemm_conv(const unsigned short* __restrict__ qb,
                                                 const unsigned short* __restrict__ ptb,
                                                 const float* __restrict__ bias,
                                                 const float* __restrict__ w,
                                                 float* __restrict__ out) {
  __shared__ unsigned short vt[128 * 68];   // 17.4KB v-tile
  const int t = threadIdx.x;
  const long mo = (long)blockIdx.x * MT;
  const int n0 = blockIdx.y * 64;
  const int lane = t & 63;
  const int wv = t >> 6;
  const int fr = lane & 15;
  const int fq = lane >> 4;

  // fragment base pointers (A rows may be <0 or >=8192: lands in d_ws apron,
  // masked at output)
  const unsigned short* pa = qb + (mo - 8 + wv * 32 + fr) * (long)ND + fq * 8;
  const unsigned short* pb = ptb + (size_t)(n0 + fr) * ND + fq * 8;

  s16x8 af[2][2], bf[2][4];
  f32x4 acc[2][4] = {};

#define LOADK(buf, kt)                                                  \
  do {                                                                  \
    const long ko_ = (long)(kt) * 32;                                   \
    _Pragma("unroll")                                                   \
    for (int m = 0; m < 2; ++m)                                         \
      af[buf][m] = *(const s16x8*)(pa + (long)m * 16 * ND + ko_);       \
    _Pragma("unroll")                                                   \
    for (int n = 0; n < 4; ++n)                                         \
      bf[buf][n] = *(const s16x8*)(pb + (long)n * 16 * ND + ko_);       \
  } while (0)

#define MMSET(buf)                                                      \
  do {                                                                  \
    _Pragma("unroll")                                                   \
    for (int m = 0; m < 2; ++m)                                         \
      _Pragma("unroll")                                                 \
      for (int n = 0; n < 4; ++n)                                       \
        acc[m][n] = __builtin_amdgcn_mfma_f32_16x16x32_bf16(            \
            af[buf][m], bf[buf][n], acc[m][n], 0, 0, 0);                \
  } while (0)

  LOADK(0, 0);
  for (int kt = 0; kt < ND / 32; kt += 2) {
    LOADK(1, kt + 1);
    MMSET(0);
    if (kt + 2 < ND / 32) LOADK(0, kt + 2);
    MMSET(1);
  }
#undef LOADK
#undef MMSET

  // dump v-tile (+bias) to LDS bf16, [128][68]
#pragma unroll
  for (int m = 0; m < 2; ++m) {
#pragma unroll
    for (int n = 0; n < 4; ++n) {
      const int rb = wv * 32 + m * 16 + fq * 4;
      const int cc = n * 16 + fr;
      const float bbv = bias[n0 + cc];
#pragma unroll
      for (int j = 0; j < 4; ++j)
        vt[(rb + j) * 68 + cc] = f2bf(acc[m][n][j] + bbv);
    }
  }
  __syncthreads();

  // conv tail: thread owns col-quad cq (16 thr x 4 = 64 cols), 7 rows.
  const int cq = (t & 15) * 4;
  const int r0 = 8 + (t >> 4) * 7;
  const int h = n0 >> 6;             // whole block = one head
  float4 win[NK];
#pragma unroll
  for (int k = 0; k < NK; ++k) {
    ushort4 u = *(const ushort4*)&vt[(r0 - 4 + k) * 68 + cq];
    win[k] = make_float4(bf2f(u.x), bf2f(u.y), bf2f(u.z), bf2f(u.w));
  }
#pragma unroll
  for (int i = 0; i < 7; ++i) {
    const int r = r0 + i;
    const long g = mo + r - 8;            // global output row (b*NL + l)
    if (g < (long)NB * NL) {
      const int l = (int)(g & (NL - 1));
      const float* wp = &w[((size_t)g * NH + h) * NK];
      float4 a = make_float4(0.f, 0.f, 0.f, 0.f);
#pragma unroll
      for (int k = 0; k < NK; ++k) {
        const int lk = l + k - NPAD;
        if (lk >= 0 && lk < NL) {
          const float wk = wp[k];
          a.x = fmaf(wk, win[k].x, a.x);
          a.y = fmaf(wk, win[k].y, a.y);
          a.z = fmaf(wk, win[k].z, a.z);
          a.w = fmaf(wk, win[k].w, a.w);
        }
      }
      *(float4*)&out[(size_t)g * ND + n0 + cq] = a;
    }
    if (i < 6) {
#pragma unroll
      for (int k = 0; k < NK - 1; ++k) win[k] = win[k + 1];
      ushort4 u = *(const ushort4*)&vt[(r + 5) * 68 + cq];
      win[NK - 1] = make_float4(bf2f(u.x), bf2f(u.y), bf2f(u.z), bf2f(u.w));
    }
  }
}

// ---------------------------------------------------------------------------
extern "C" void kernel_launch(void* const* d_in, const int* in_sizes, int n_in,
                              void* d_out, int out_size, void* d_ws, size_t ws_size,
                              hipStream_t stream) {
  const float* query = (const float*)d_in[0];
  const float* dw_w  = (const float*)d_in[1];
  const float* pw_w  = (const float*)d_in[2];
  const float* pw_b  = (const float*)d_in[3];
  const float* ak_w  = (const float*)d_in[4];
  const float* ak_b  = (const float*)d_in[5];
  const float* pt_w  = (const float*)d_in[6];
  const float* pt_b  = (const float*)d_in[7];
  float* out = (float*)d_out;

  // workspace: w first (gives qb a safe negative-offset apron), then qb, ptb…
  float* w = (float*)d_ws;                                        // 3.54MB
  unsigned short* qb  = (unsigned short*)(w + (size_t)NB * NL * NH * NK); // 12.6MB
  unsigned short* ptb = qb + (size_t)NB * NL * ND;                // 1.18MB
  unsigned short* pwb = ptb + (size_t)ND * ND;                    // 98KB
  unsigned short* akp = pwb + (size_t)NH * NIPG * NIPG;           // 24.6KB

  prep<<<ND * ND / 4 / 256, 256, 0, stream>>>(pt_w, pw_w, ak_w, ptb, pwb, akp);

  dim3 g2(NL / 64, NH, NB);
  attn_w<<<g2, 256, 0, stream>>>(query, dw_w, pwb, pw_b, akp, ak_b, w, qb);

  dim3 g3((NB * NL + MT - 1) / MT, ND / 64, 1);
  gemm_conv<<<g3, 256, 0, stream>>>(qb, ptb, pt_b, w, out);
}

// Round 7
// 160.353 us; speedup vs baseline: 1.1691x; 1.1691x over previous
//
#include <hip/hip_runtime.h>
#include <math.h>

#define NB 4
#define NL 2048
#define ND 768
#define NH 12
#define NK 9
#define NIPG 64
#define NPAD 4
#define MT 240          // output rows per gemm_conv block (computes 256 v-rows)

typedef __attribute__((ext_vector_type(8))) short s16x8;
typedef __attribute__((ext_vector_type(4))) float f32x4;

__device__ __forceinline__ unsigned short f2bf(float f) {
  unsigned int u = __float_as_uint(f);
  unsigned int r = (u + 0x7FFFu + ((u >> 16) & 1u)) >> 16;
  return (unsigned short)r;
}
__device__ __forceinline__ float bf2f(unsigned short s) {
  return __uint_as_float(((unsigned int)s) << 16);
}
__device__ __forceinline__ void gload16(const void* g, void* l) {
  __builtin_amdgcn_global_load_lds((const __attribute__((address_space(1))) void*)g,
                                   (__attribute__((address_space(3))) void*)l,
                                   16, 0, 0);
}

// ---------------------------------------------------------------------------
// Kernel 0: weight prep — pt_w -> ptb (bf16), pw_w -> pwb, ak_w -> akp
// ---------------------------------------------------------------------------
__global__ __launch_bounds__(256) void prep(const float* __restrict__ pt_w,
                                            const float* __restrict__ pw_w,
                                            const float* __restrict__ ak_w,
                                            unsigned short* __restrict__ ptb,
                                            unsigned short* __restrict__ pwb,
                                            unsigned short* __restrict__ akp) {
  const int t = blockIdx.x * 256 + threadIdx.x;
  if (t < ND * ND / 4) {
    float4 f = ((const float4*)pt_w)[t];
    ushort4 o; o.x = f2bf(f.x); o.y = f2bf(f.y); o.z = f2bf(f.z); o.w = f2bf(f.w);
    ((ushort4*)ptb)[t] = o;
  }
  if (t < NH * NIPG * NIPG / 4) {
    float4 f = ((const float4*)pw_w)[t];
    ushort4 o; o.x = f2bf(f.x); o.y = f2bf(f.y); o.z = f2bf(f.z); o.w = f2bf(f.w);
    ((ushort4*)pwb)[t] = o;
  }
  if (t < NH * 16 * NIPG) {
    const int h = t >> 10;
    const int r = t & 1023;
    const int k = r >> 6;
    const int i = r & 63;
    akp[t] = (k < NK) ? f2bf(ak_w[((size_t)h * NK + k) * NIPG + i]) : (unsigned short)0;
  }
}

// ---------------------------------------------------------------------------
// Kernel 1: dynamic conv weights (MFMA) + emits qb = bf16(query).
// Unchanged from round 6 (passed; one barrier, wave-private ab rows).
// ---------------------------------------------------------------------------
__global__ __launch_bounds__(256) void attn_w(const float* __restrict__ q,
                                              const float* __restrict__ dw_w,
                                              const unsigned short* __restrict__ pwb,
                                              const float* __restrict__ pw_b,
                                              const unsigned short* __restrict__ akp,
                                              const float* __restrict__ ak_b,
                                              float* __restrict__ wout,
                                              unsigned short* __restrict__ qb) {
  __shared__ unsigned short qs[72][68];
  __shared__ unsigned char ab[8192];
  const int l0 = blockIdx.x * 64;
  const int h  = blockIdx.y;
  const int b  = blockIdx.z;
  const int d0 = h * NIPG;
  const int t  = threadIdx.x;
  const int lane = t & 63;
  const int wv = t >> 6;
  const int fr = lane & 15;
  const int fq = lane >> 4;

  const unsigned short* pwh = pwb + (size_t)h * NIPG * NIPG;
  const unsigned short* akh = akp + (size_t)h * 16 * NIPG;
  s16x8 pv0[4], pv1[4];
#pragma unroll
  for (int n = 0; n < 4; ++n) {
    const int o = n * 16 + fr;
    pv0[n] = *(const s16x8*)&pwh[o * 64 + fq * 8];
    pv1[n] = *(const s16x8*)&pwh[o * 64 + 32 + fq * 8];
  }
  s16x8 ak0 = *(const s16x8*)&akh[fr * 64 + fq * 8];
  s16x8 ak1 = *(const s16x8*)&akh[fr * 64 + 32 + fq * 8];
  float dwk[NK];
#pragma unroll
  for (int k = 0; k < NK; ++k) dwk[k] = dw_w[(size_t)(d0 + lane) * NK + k];

  {
    const int sl = t >> 4;
    const int sc = (t & 15) * 4;
    for (int r = sl; r < 72; r += 16) {
      const int l = l0 - NPAD + r;
      ushort4 ub = make_ushort4(0, 0, 0, 0);
      if (l >= 0 && l < NL) {
        float4 val = *(const float4*)&q[((size_t)(b * NL + l)) * ND + d0 + sc];
        ub.x = f2bf(val.x); ub.y = f2bf(val.y); ub.z = f2bf(val.z); ub.w = f2bf(val.w);
        if (r >= NPAD && r < NPAD + 64)
          *(ushort4*)&qb[((size_t)(b * NL + l)) * ND + d0 + sc] = ub;
      }
      *(ushort4*)&qs[r][sc] = ub;
    }
  }
  __syncthreads();

  const int lset = wv * 16;
  {
    float win9[NK];
#pragma unroll
    for (int k = 0; k < NK; ++k) win9[k] = bf2f(qs[lset + k][lane]);
#pragma unroll
    for (int l2 = 0; l2 < 16; ++l2) {
      const int l = lset + l2;
      float s = 0.f;
#pragma unroll
      for (int k = 0; k < NK; ++k) s = fmaf(win9[k], dwk[k], s);
      const int byte = ((l * 64 + lane) * 2) ^ ((l & 7) << 4);
      *(unsigned short*)&ab[byte] = f2bf(s);
      if (l2 < 15) {
#pragma unroll
        for (int k = 0; k < NK - 1; ++k) win9[k] = win9[k + 1];
        win9[NK - 1] = bf2f(qs[lset + l2 + NK][lane]);
      }
    }
  }

  s16x8 av0, av1;
  {
    const int row = lset + fr;
    const int b0 = ((row * 64 + fq * 8) * 2)      ^ ((row & 7) << 4);
    const int b1 = ((row * 64 + 32 + fq * 8) * 2) ^ ((row & 7) << 4);
    av0 = *(const s16x8*)&ab[b0];
    av1 = *(const s16x8*)&ab[b1];
  }
  f32x4 accp[4];
#pragma unroll
  for (int n = 0; n < 4; ++n) {
    accp[n] = (f32x4){0.f, 0.f, 0.f, 0.f};
    accp[n] = __builtin_amdgcn_mfma_f32_16x16x32_bf16(av0, pv0[n], accp[n], 0, 0, 0);
    accp[n] = __builtin_amdgcn_mfma_f32_16x16x32_bf16(av1, pv1[n], accp[n], 0, 0, 0);
  }

#pragma unroll
  for (int n = 0; n < 4; ++n) {
    const int o = n * 16 + fr;
    const float pb = pw_b[d0 + o];
#pragma unroll
    for (int j = 0; j < 4; ++j) {
      const int row = lset + fq * 4 + j;
      const float ca = (accp[n][j] + pb) * bf2f(qs[row + NPAD][o]);
      const int byte = ((row * 64 + o) * 2) ^ ((row & 7) << 4);
      *(unsigned short*)&ab[byte] = f2bf(ca);
    }
  }

  f32x4 acck = (f32x4){0.f, 0.f, 0.f, 0.f};
  {
    const int row = lset + fr;
    const int b0 = ((row * 64 + fq * 8) * 2)      ^ ((row & 7) << 4);
    const int b1 = ((row * 64 + 32 + fq * 8) * 2) ^ ((row & 7) << 4);
    s16x8 a0 = *(const s16x8*)&ab[b0];
    s16x8 a1 = *(const s16x8*)&ab[b1];
    acck = __builtin_amdgcn_mfma_f32_16x16x32_bf16(a0, ak0, acck, 0, 0, 0);
    acck = __builtin_amdgcn_mfma_f32_16x16x32_bf16(a1, ak1, acck, 0, 0, 0);
  }

  const bool kvalid = fr < NK;
  const float akbv = kvalid ? ak_b[h * NK + fr] : 0.f;
#pragma unroll
  for (int j = 0; j < 4; ++j) {
    float val = acck[j] + akbv;
    float mv = kvalid ? val : -3.4e38f;
#pragma unroll
    for (int mm = 1; mm < 16; mm <<= 1) mv = fmaxf(mv, __shfl_xor(mv, mm));
    const float e = kvalid ? __expf(val - mv) : 0.f;
    float ssum = e;
#pragma unroll
    for (int mm = 1; mm < 16; mm <<= 1) ssum += __shfl_xor(ssum, mm);
    if (kvalid) {
      const int row = l0 + lset + fq * 4 + j;
      wout[(((size_t)(b * NL + row)) * NH + h) * NK + fr] = e / ssum;
    }
  }
}

// ---------------------------------------------------------------------------
// Kernel 2: fused v-GEMM + 9-tap conv.  256(M)x64(N) tile, BK=32, 4 waves x
// 64 rows.  Counted-vmcnt pipeline (T3+T4): stage via global_load_lds into
// 2x20KB buffers, s_waitcnt vmcnt(5) + raw s_barrier per K-step — loads stay
// in flight across barriers, never drained to 0 until the peeled tail.
// Global source pre-swizzled (slot ^= (row>>1)&3) so LDS frag reads are
// ~conflict-free (T2, m173 pattern).  LDS 75.8KB -> 2 blocks/CU.
// ---------------------------------------------------------------------------
__global__ __launch_bounds__(256, 2) void gemm_conv(const unsigned short* __restrict__ qb,
                                                    const unsigned short* __restrict__ ptb,
                                                    const float* __restrict__ bias,
                                                    const float* __restrict__ w,
                                                    float* __restrict__ out) {
  // [0,40960): 2 x {A 16KB | B 4KB} stage buffers; [40960,75776): vt tile
  __shared__ unsigned char smem[75776];
  unsigned short* vt = (unsigned short*)(smem + 40960);
  const int t = threadIdx.x;
  const long mo = (long)blockIdx.x * MT;
  const int n0 = blockIdx.y * 64;
  const int lane = t & 63;
  const int wv = t >> 6;
  const int fr = lane & 15;
  const int fq = lane >> 4;

  // pre-swizzled per-lane global byte pointers (m173: linear LDS dest,
  // swizzle source + read).  lane l stages row (l>>2), 16B-slot
  // (l&3)^((l>>3)&3) of each 16-row chunk.
  const int slotp = (((lane & 3) ^ ((lane >> 3) & 3))) * 16;
  const unsigned char* gA = (const unsigned char*)qb + (mo - 8 + (lane >> 2)) * 1536L + slotp;
  const unsigned char* gB = (const unsigned char*)ptb + (size_t)(n0 + (lane >> 2)) * 1536 + slotp;

  // fragment LDS byte offsets (read-side swizzle matches source swizzle)
  const int srd = (fq ^ ((fr >> 1) & 3)) * 16;
  int aoffb[4], boffb[4];
#pragma unroll
  for (int m = 0; m < 4; ++m) aoffb[m] = (wv * 4 + m) * 1024 + fr * 64 + srd;
#pragma unroll
  for (int n = 0; n < 4; ++n) boffb[n] = 16384 + n * 1024 + fr * 64 + srd;

  // wave wv stages chunks [5wv, 5wv+5): chunks 0-15 = A rows c*16..,
  // chunks 16-19 = B rows (c-16)*16..   (uniform 5 vmem ops per lane)
#define STAGE(kt_)                                                          \
  do {                                                                      \
    unsigned char* sb_ = smem + ((kt_) & 1) * 20480;                        \
    const long kb_ = (long)(kt_) * 64;                                      \
    _Pragma("unroll")                                                       \
    for (int j_ = 0; j_ < 5; ++j_) {                                        \
      const int c_ = wv * 5 + j_;                                           \
      const unsigned char* g_ = (c_ < 16)                                   \
          ? (gA + (long)c_ * 24576 + kb_)                                   \
          : (gB + (long)(c_ - 16) * 24576 + kb_);                           \
      gload16(g_, sb_ + c_ * 1024 + lane * 16);                             \
    }                                                                       \
  } while (0)

#define LOADFRAGS(kt_)                                                      \
  do {                                                                      \
    const unsigned char* sb_ = smem + ((kt_) & 1) * 20480;                  \
    _Pragma("unroll")                                                       \
    for (int m_ = 0; m_ < 4; ++m_) av[m_] = *(const s16x8*)(sb_ + aoffb[m_]); \
    _Pragma("unroll")                                                       \
    for (int n_ = 0; n_ < 4; ++n_) bv[n_] = *(const s16x8*)(sb_ + boffb[n_]); \
  } while (0)

#define MM16                                                                \
  do {                                                                      \
    _Pragma("unroll")                                                       \
    for (int m_ = 0; m_ < 4; ++m_)                                          \
      _Pragma("unroll")                                                     \
      for (int n_ = 0; n_ < 4; ++n_)                                        \
        acc[m_][n_] = __builtin_amdgcn_mfma_f32_16x16x32_bf16(              \
            av[m_], bv[n_], acc[m_][n_], 0, 0, 0);                          \
  } while (0)

  f32x4 acc[4][4] = {};
  s16x8 av[4], bv[4];

  STAGE(0);
  STAGE(1);
  for (int kt = 0; kt < 22; ++kt) {
    asm volatile("s_waitcnt vmcnt(5)" ::: "memory");   // kt's 5 done; kt+1 in flight
    __builtin_amdgcn_s_barrier();                      // all waves' kt-stage done
    LOADFRAGS(kt);
    asm volatile("s_waitcnt lgkmcnt(0)" ::: "memory"); // my reads complete
    __builtin_amdgcn_sched_barrier(0);
    __builtin_amdgcn_s_barrier();                      // everyone's reads complete
    STAGE(kt + 2);                                     // overwrite buf kt&1
    MM16;
  }
  {  // kt = 22
    asm volatile("s_waitcnt vmcnt(5)" ::: "memory");
    __builtin_amdgcn_s_barrier();
    LOADFRAGS(22);
    MM16;
  }
  {  // kt = 23
    asm volatile("s_waitcnt vmcnt(0)" ::: "memory");
    __builtin_amdgcn_s_barrier();
    LOADFRAGS(23);
    MM16;
  }
#undef STAGE
#undef LOADFRAGS
#undef MM16

  // dump v-tile (+bias) to LDS bf16, [256][68]
#pragma unroll
  for (int m = 0; m < 4; ++m) {
#pragma unroll
    for (int n = 0; n < 4; ++n) {
      const int rb = wv * 64 + m * 16 + fq * 4;
      const int cc = n * 16 + fr;
      const float bbv = bias[n0 + cc];
#pragma unroll
      for (int j = 0; j < 4; ++j)
        vt[(rb + j) * 68 + cc] = f2bf(acc[m][n][j] + bbv);
    }
  }
  __syncthreads();

  // conv tail: thread owns col-quad cq (16 thr x 4 = 64 cols), 15 rows.
  const int cq = (t & 15) * 4;
  const int r0 = 8 + (t >> 4) * 15;
  const int h = n0 >> 6;
  float4 win[NK];
#pragma unroll
  for (int k = 0; k < NK; ++k) {
    ushort4 u = *(const ushort4*)&vt[(r0 - 4 + k) * 68 + cq];
    win[k] = make_float4(bf2f(u.x), bf2f(u.y), bf2f(u.z), bf2f(u.w));
  }
#pragma unroll
  for (int i = 0; i < 15; ++i) {
    const int r = r0 + i;
    const long g = mo + r - 8;
    if (g < (long)NB * NL) {
      const int l = (int)(g & (NL - 1));
      const float* wp = &w[((size_t)g * NH + h) * NK];
      float4 a = make_float4(0.f, 0.f, 0.f, 0.f);
#pragma unroll
      for (int k = 0; k < NK; ++k) {
        const int lk = l + k - NPAD;
        if (lk >= 0 && lk < NL) {
          const float wk = wp[k];
          a.x = fmaf(wk, win[k].x, a.x);
          a.y = fmaf(wk, win[k].y, a.y);
          a.z = fmaf(wk, win[k].z, a.z);
          a.w = fmaf(wk, win[k].w, a.w);
        }
      }
      *(float4*)&out[(size_t)g * ND + n0 + cq] = a;
    }
    if (i < 14) {
#pragma unroll
      for (int k = 0; k < NK - 1; ++k) win[k] = win[k + 1];
      ushort4 u = *(const ushort4*)&vt[(r + 5) * 68 + cq];
      win[NK - 1] = make_float4(bf2f(u.x), bf2f(u.y), bf2f(u.z), bf2f(u.w));
    }
  }
}

// ---------------------------------------------------------------------------
extern "C" void kernel_launch(void* const* d_in, const int* in_sizes, int n_in,
                              void* d_out, int out_size, void* d_ws, size_t ws_size,
                              hipStream_t stream) {
  const float* query = (const float*)d_in[0];
  const float* dw_w  = (const float*)d_in[1];
  const float* pw_w  = (const float*)d_in[2];
  const float* pw_b  = (const float*)d_in[3];
  const float* ak_w  = (const float*)d_in[4];
  const float* ak_b  = (const float*)d_in[5];
  const float* pt_w  = (const float*)d_in[6];
  const float* pt_b  = (const float*)d_in[7];
  float* out = (float*)d_out;

  // workspace: w first (gives qb a safe apron both sides), then qb, ptb…
  float* w = (float*)d_ws;                                        // 3.54MB
  unsigned short* qb  = (unsigned short*)(w + (size_t)NB * NL * NH * NK); // 12.6MB
  unsigned short* ptb = qb + (size_t)NB * NL * ND;                // 1.18MB
  unsigned short* pwb = ptb + (size_t)ND * ND;                    // 98KB
  unsigned short* akp = pwb + (size_t)NH * NIPG * NIPG;           // 24.6KB

  prep<<<ND * ND / 4 / 256, 256, 0, stream>>>(pt_w, pw_w, ak_w, ptb, pwb, akp);

  dim3 g2(NL / 64, NH, NB);
  attn_w<<<g2, 256, 0, stream>>>(query, dw_w, pwb, pw_b, akp, ak_b, w, qb);

  dim3 g3((NB * NL + MT - 1) / MT, ND / 64, 1);
  gemm_conv<<<g3, 256, 0, stream>>>(qb, ptb, pt_b, w, out);
}